// Round 5
// baseline (87.612 us; speedup 1.0000x reference)
//
#include <hip/hip_runtime.h>
#include <hip/hip_bf16.h>
#include <cstdint>

#define LN2F 0.69314718056f

__device__ __forceinline__ float ssp(float x) {
    return fmaxf(x, 0.0f) + log1pf(expf(-fabsf(x))) - LN2F;
}

__device__ __forceinline__ uint16_t f2bf_rne(float x) {
    uint32_t u = __float_as_uint(x);
    u += 0x7FFF + ((u >> 16) & 1u);
    return (uint16_t)(u >> 16);
}

__device__ __forceinline__ float bf_lo(uint32_t u) { return __uint_as_float(u << 16); }
__device__ __forceinline__ float bf_hi(uint32_t u) { return __uint_as_float(u & 0xffff0000u); }

// ---------------------------------------------------------------------------
// prep: blocks [0,256): v1 = (m*(v@W_a1) + b_a1) * m   (8 rows/block)
//       blocks [256,768): filter table T[g][d] = F(g*0.0025)[d] bf16 (8 g/block)
// F(d) = ssp( ssp(rbf(d) @ W_s1 + b_s1) @ W_s2 + b_s2 )
// ---------------------------------------------------------------------------
__global__ __launch_bounds__(512) void prep_kernel(
    const float* __restrict__ v, const float* __restrict__ mask,
    const float* __restrict__ W_a1, const float* __restrict__ b_a1,
    const float* __restrict__ W_s1, const float* __restrict__ b_s1,
    const float* __restrict__ W_s2, const float* __restrict__ b_s2,
    float* __restrict__ v1, uint16_t* __restrict__ T) {
    __shared__ float sA[8][304];
    __shared__ float sB[8][64];
    const int t = threadIdx.x;

    if (blockIdx.x < 256) {
        // ---------------- linear role ----------------
        const int r0 = blockIdx.x * 8;
        for (int e = t; e < 2048; e += 512) {
            int row = e >> 8, c = e & 255;
            sA[row][c] = v[(r0 + row) * 256 + c];
        }
        __syncthreads();
        const int col = t & 255;
        const int g = t >> 8;
        const int c0 = blockIdx.x & 15;
        float acc[4] = {0.f, 0.f, 0.f, 0.f};
        float w[16], wn[16];
        {
            const int kt = c0 * 16;
            #pragma unroll
            for (int q = 0; q < 16; ++q) w[q] = W_a1[(kt + q) * 256 + col];
        }
        for (int i = 0; i < 16; ++i) {
            const int kt = ((c0 + i) & 15) * 16;
            if (i < 15) {
                const int ktn = ((c0 + i + 1) & 15) * 16;
                #pragma unroll
                for (int q = 0; q < 16; ++q) wn[q] = W_a1[(ktn + q) * 256 + col];
            }
            #pragma unroll
            for (int q4 = 0; q4 < 4; ++q4) {
                const int k = kt + q4 * 4;
                const float w0 = w[q4 * 4 + 0], w1 = w[q4 * 4 + 1];
                const float w2 = w[q4 * 4 + 2], w3 = w[q4 * 4 + 3];
                #pragma unroll
                for (int rr = 0; rr < 4; ++rr) {
                    const float4 xv = *(const float4*)&sA[g * 4 + rr][k];
                    float a = acc[rr];
                    a = fmaf(xv.x, w0, a);
                    a = fmaf(xv.y, w1, a);
                    a = fmaf(xv.z, w2, a);
                    a = fmaf(xv.w, w3, a);
                    acc[rr] = a;
                }
            }
            if (i < 15) {
                #pragma unroll
                for (int q = 0; q < 16; ++q) w[q] = wn[q];
            }
        }
        const float b = b_a1[col];
        #pragma unroll
        for (int rr = 0; rr < 4; ++rr) {
            const int r = r0 + g * 4 + rr;
            const float m = mask[r];
            v1[r * 256 + col] = (acc[rr] * m + b) * m;
        }
    } else {
        // ---------------- table role ----------------
        const int g0 = (blockIdx.x - 256) * 8;
        #pragma unroll
        for (int gg = 0; gg < 8; ++gg) {
            if (t < 300) {
                float d = (float)(g0 + gg) * 0.0025f;
                float diff = d - 0.1f * (float)t;
                sA[gg][t] = expf(-10.f * diff * diff);
            }
        }
        __syncthreads();
        {
            int gg = t >> 6, c = t & 63;
            float acc = b_s1[c];
            for (int r = 0; r < 300; ++r)
                acc = fmaf(sA[gg][r], W_s1[r * 64 + c], acc);
            sB[gg][c] = ssp(acc);
        }
        __syncthreads();
        {
            int col = t & 255, glo = t >> 8;
            float bb = b_s2[col];
            float val[4];
            #pragma unroll
            for (int q = 0; q < 4; ++q) val[q] = bb;
            for (int c = 0; c < 64; ++c) {
                float w = W_s2[c * 256 + col];
                #pragma unroll
                for (int q = 0; q < 4; ++q)
                    val[q] = fmaf(sB[glo + 2 * q][c], w, val[q]);
            }
            #pragma unroll
            for (int q = 0; q < 4; ++q) {
                int g = g0 + glo + 2 * q;
                T[g * 256 + col] = f2bf_rne(ssp(val[q]));
            }
        }
    }
}

// ---------------------------------------------------------------------------
// main: 512 blocks x 256 thr, 4 rows/block (2 blocks/CU):
//   mid[r,:] = sum_j T[round(d/h)][:] * v1[b,j,:]   (v1 direct from L1/L2,
//                                                    no staging barriers)
//   y  = ssp((mid*m) @ W_a2 + b_a2) * m             (mid*m in LDS)
//   out = (y @ W_a3 + b_a3) * m                     (y in LDS)
// Gather: h = t>>6 row (wave-uniform), p = t&63 owns dims 4p..4p+3.
// ---------------------------------------------------------------------------
__global__ __launch_bounds__(256, 2) void main_kernel(
    const float* __restrict__ dist, const float* __restrict__ v1,
    const uint16_t* __restrict__ T, const float* __restrict__ mask,
    const float* __restrict__ W_a2, const float* __restrict__ b_a2,
    const float* __restrict__ W_a3, const float* __restrict__ b_a3,
    float* __restrict__ out) {
    __shared__ uint32_t sk[4][256];   // 4 KB table byte offsets
    __shared__ float xs[4][256];      // 4 KB activation rows
    const int t = threadIdx.x;
    const int r0 = blockIdx.x * 4;
    const int b = r0 >> 8;
    const int h = t >> 6;             // row within block (wave-uniform)
    const int p = t & 63;             // dims 4p..4p+3

    for (int e = t; e < 1024; e += 256) {
        int row = e >> 8, j = e & 255;
        float d = dist[(r0 + row) * 256 + j];
        int k = (int)fmaf(d, 400.f, 0.5f);   // nearest grid point, step 0.0025
        k = min(k, 4095);
        sk[row][j] = (uint32_t)(k << 9);     // byte offset (512 B per table row)
    }
    __syncthreads();

    float a0 = 0.f, a1 = 0.f, a2 = 0.f, a3 = 0.f;
    const char* Tp = (const char*)T + (p << 3);
    const float* vb = v1 + ((size_t)b << 16) + (p << 2);

    #pragma unroll 4
    for (int jj = 0; jj < 256; jj += 4) {
        const uint4 kk = *(const uint4*)&sk[h][jj];
        const uint2 u0 = *(const uint2*)(Tp + kk.x);
        const uint2 u1 = *(const uint2*)(Tp + kk.y);
        const uint2 u2 = *(const uint2*)(Tp + kk.z);
        const uint2 u3 = *(const uint2*)(Tp + kk.w);
        const float4 w0 = *(const float4*)(vb + ((jj + 0) << 8));
        const float4 w1 = *(const float4*)(vb + ((jj + 1) << 8));
        const float4 w2 = *(const float4*)(vb + ((jj + 2) << 8));
        const float4 w3 = *(const float4*)(vb + ((jj + 3) << 8));
        a0 = fmaf(bf_lo(u0.x), w0.x, a0);
        a1 = fmaf(bf_hi(u0.x), w0.y, a1);
        a2 = fmaf(bf_lo(u0.y), w0.z, a2);
        a3 = fmaf(bf_hi(u0.y), w0.w, a3);
        a0 = fmaf(bf_lo(u1.x), w1.x, a0);
        a1 = fmaf(bf_hi(u1.x), w1.y, a1);
        a2 = fmaf(bf_lo(u1.y), w1.z, a2);
        a3 = fmaf(bf_hi(u1.y), w1.w, a3);
        a0 = fmaf(bf_lo(u2.x), w2.x, a0);
        a1 = fmaf(bf_hi(u2.x), w2.y, a1);
        a2 = fmaf(bf_lo(u2.y), w2.z, a2);
        a3 = fmaf(bf_hi(u2.y), w2.w, a3);
        a0 = fmaf(bf_lo(u3.x), w3.x, a0);
        a1 = fmaf(bf_hi(u3.x), w3.y, a1);
        a2 = fmaf(bf_lo(u3.y), w3.z, a2);
        a3 = fmaf(bf_hi(u3.y), w3.w, a3);
    }
    {   // mid * mask -> xs
        const float m = mask[r0 + h];
        *(float4*)&xs[h][p * 4] = make_float4(a0 * m, a1 * m, a2 * m, a3 * m);
    }
    __syncthreads();

    // ---------------- a2 then a3, activations resident in LDS ----------------
    const int col = t;
    const int c0 = blockIdx.x & 15;

    float acc[4] = {0.f, 0.f, 0.f, 0.f};
    {
        float w[16], wn[16];
        {
            const int kt = c0 * 16;
            #pragma unroll
            for (int q = 0; q < 16; ++q) w[q] = W_a2[(kt + q) * 256 + col];
        }
        for (int i = 0; i < 16; ++i) {
            const int kt = ((c0 + i) & 15) * 16;
            if (i < 15) {
                const int ktn = ((c0 + i + 1) & 15) * 16;
                #pragma unroll
                for (int q = 0; q < 16; ++q) wn[q] = W_a2[(ktn + q) * 256 + col];
            }
            #pragma unroll
            for (int q4 = 0; q4 < 4; ++q4) {
                const int k = kt + q4 * 4;
                const float w0 = w[q4 * 4 + 0], w1 = w[q4 * 4 + 1];
                const float w2 = w[q4 * 4 + 2], w3 = w[q4 * 4 + 3];
                #pragma unroll
                for (int rr = 0; rr < 4; ++rr) {
                    const float4 xv = *(const float4*)&xs[rr][k];
                    float a = acc[rr];
                    a = fmaf(xv.x, w0, a);
                    a = fmaf(xv.y, w1, a);
                    a = fmaf(xv.z, w2, a);
                    a = fmaf(xv.w, w3, a);
                    acc[rr] = a;
                }
            }
            if (i < 15) {
                #pragma unroll
                for (int q = 0; q < 16; ++q) w[q] = wn[q];
            }
        }
    }
    float y[4];
    {
        const float b2 = b_a2[col];
        #pragma unroll
        for (int rr = 0; rr < 4; ++rr)
            y[rr] = ssp(acc[rr] + b2) * mask[r0 + rr];
    }
    __syncthreads();
    #pragma unroll
    for (int rr = 0; rr < 4; ++rr) xs[rr][col] = y[rr];
    __syncthreads();

    float acc3[4] = {0.f, 0.f, 0.f, 0.f};
    {
        float w[16], wn[16];
        {
            const int kt = c0 * 16;
            #pragma unroll
            for (int q = 0; q < 16; ++q) w[q] = W_a3[(kt + q) * 256 + col];
        }
        for (int i = 0; i < 16; ++i) {
            const int kt = ((c0 + i) & 15) * 16;
            if (i < 15) {
                const int ktn = ((c0 + i + 1) & 15) * 16;
                #pragma unroll
                for (int q = 0; q < 16; ++q) wn[q] = W_a3[(ktn + q) * 256 + col];
            }
            #pragma unroll
            for (int q4 = 0; q4 < 4; ++q4) {
                const int k = kt + q4 * 4;
                const float w0 = w[q4 * 4 + 0], w1 = w[q4 * 4 + 1];
                const float w2 = w[q4 * 4 + 2], w3 = w[q4 * 4 + 3];
                #pragma unroll
                for (int rr = 0; rr < 4; ++rr) {
                    const float4 xv = *(const float4*)&xs[rr][k];
                    float a = acc3[rr];
                    a = fmaf(xv.x, w0, a);
                    a = fmaf(xv.y, w1, a);
                    a = fmaf(xv.z, w2, a);
                    a = fmaf(xv.w, w3, a);
                    acc3[rr] = a;
                }
            }
            if (i < 15) {
                #pragma unroll
                for (int q = 0; q < 16; ++q) w[q] = wn[q];
            }
        }
    }
    {
        const float b3 = b_a3[col];
        #pragma unroll
        for (int rr = 0; rr < 4; ++rr) {
            const int r = r0 + rr;
            out[r * 256 + col] = (acc3[rr] + b3) * mask[r];
        }
    }
}

// ---------------------------------------------------------------------------
extern "C" void kernel_launch(void* const* d_in, const int* in_sizes, int n_in,
                              void* d_out, int out_size, void* d_ws, size_t ws_size,
                              hipStream_t stream) {
    const float* v    = (const float*)d_in[0];
    const float* dist = (const float*)d_in[1];
    const float* mask = (const float*)d_in[2];
    const float* W_s1 = (const float*)d_in[3];
    const float* b_s1 = (const float*)d_in[4];
    const float* W_s2 = (const float*)d_in[5];
    const float* b_s2 = (const float*)d_in[6];
    const float* W_a1 = (const float*)d_in[7];
    const float* b_a1 = (const float*)d_in[8];
    const float* W_a2 = (const float*)d_in[9];
    const float* b_a2 = (const float*)d_in[10];
    const float* W_a3 = (const float*)d_in[11];
    const float* b_a3 = (const float*)d_in[12];
    float* out = (float*)d_out;

    char* ws = (char*)d_ws;
    float*    v1 = (float*)(ws);                   // 2 MB
    uint16_t* T  = (uint16_t*)(ws + (2u << 20));   // 2 MB bf16 [4096][256]

    prep_kernel<<<768, 512, 0, stream>>>(v, mask, W_a1, b_a1, W_s1, b_s1, W_s2, b_s2, v1, T);
    main_kernel<<<512, 256, 0, stream>>>(dist, v1, T, mask, W_a2, b_a2, W_a3, b_a3, out);
}

// Round 6
// 84.081 us; speedup vs baseline: 1.0420x; 1.0420x over previous
//
#include <hip/hip_runtime.h>
#include <hip/hip_bf16.h>
#include <cstdint>

#define LN2F 0.69314718056f

__device__ __forceinline__ float ssp(float x) {
    return fmaxf(x, 0.0f) + log1pf(expf(-fabsf(x))) - LN2F;
}

__device__ __forceinline__ uint16_t f2bf_rne(float x) {
    uint32_t u = __float_as_uint(x);
    u += 0x7FFF + ((u >> 16) & 1u);
    return (uint16_t)(u >> 16);
}

__device__ __forceinline__ float bf_lo(uint32_t u) { return __uint_as_float(u << 16); }
__device__ __forceinline__ float bf_hi(uint32_t u) { return __uint_as_float(u & 0xffff0000u); }

// ---------------------------------------------------------------------------
// prep: blocks [0,256): v1 = (m*(v@W_a1) + b_a1) * m   (8 rows/block)
//       blocks [256,768): filter table T[g][d] = F(g*0.0025)[d] bf16 (8 g/block)
// ---------------------------------------------------------------------------
__global__ __launch_bounds__(512) void prep_kernel(
    const float* __restrict__ v, const float* __restrict__ mask,
    const float* __restrict__ W_a1, const float* __restrict__ b_a1,
    const float* __restrict__ W_s1, const float* __restrict__ b_s1,
    const float* __restrict__ W_s2, const float* __restrict__ b_s2,
    float* __restrict__ v1, uint16_t* __restrict__ T) {
    __shared__ float sA[8][304];
    __shared__ float sB[8][64];
    const int t = threadIdx.x;

    if (blockIdx.x < 256) {
        const int r0 = blockIdx.x * 8;
        for (int e = t; e < 2048; e += 512) {
            int row = e >> 8, c = e & 255;
            sA[row][c] = v[(r0 + row) * 256 + c];
        }
        __syncthreads();
        const int col = t & 255;
        const int g = t >> 8;
        const int c0 = blockIdx.x & 15;
        float acc[4] = {0.f, 0.f, 0.f, 0.f};
        float w[16], wn[16];
        {
            const int kt = c0 * 16;
            #pragma unroll
            for (int q = 0; q < 16; ++q) w[q] = W_a1[(kt + q) * 256 + col];
        }
        for (int i = 0; i < 16; ++i) {
            const int kt = ((c0 + i) & 15) * 16;
            if (i < 15) {
                const int ktn = ((c0 + i + 1) & 15) * 16;
                #pragma unroll
                for (int q = 0; q < 16; ++q) wn[q] = W_a1[(ktn + q) * 256 + col];
            }
            #pragma unroll
            for (int q4 = 0; q4 < 4; ++q4) {
                const int k = kt + q4 * 4;
                const float w0 = w[q4 * 4 + 0], w1 = w[q4 * 4 + 1];
                const float w2 = w[q4 * 4 + 2], w3 = w[q4 * 4 + 3];
                #pragma unroll
                for (int rr = 0; rr < 4; ++rr) {
                    const float4 xv = *(const float4*)&sA[g * 4 + rr][k];
                    float a = acc[rr];
                    a = fmaf(xv.x, w0, a);
                    a = fmaf(xv.y, w1, a);
                    a = fmaf(xv.z, w2, a);
                    a = fmaf(xv.w, w3, a);
                    acc[rr] = a;
                }
            }
            if (i < 15) {
                #pragma unroll
                for (int q = 0; q < 16; ++q) w[q] = wn[q];
            }
        }
        const float b = b_a1[col];
        #pragma unroll
        for (int rr = 0; rr < 4; ++rr) {
            const int r = r0 + g * 4 + rr;
            const float m = mask[r];
            v1[r * 256 + col] = (acc[rr] * m + b) * m;
        }
    } else {
        const int g0 = (blockIdx.x - 256) * 8;
        #pragma unroll
        for (int gg = 0; gg < 8; ++gg) {
            if (t < 300) {
                float d = (float)(g0 + gg) * 0.0025f;
                float diff = d - 0.1f * (float)t;
                sA[gg][t] = expf(-10.f * diff * diff);
            }
        }
        __syncthreads();
        {
            int gg = t >> 6, c = t & 63;
            float acc = b_s1[c];
            for (int r = 0; r < 300; ++r)
                acc = fmaf(sA[gg][r], W_s1[r * 64 + c], acc);
            sB[gg][c] = ssp(acc);
        }
        __syncthreads();
        {
            int col = t & 255, glo = t >> 8;
            float bb = b_s2[col];
            float val[4];
            #pragma unroll
            for (int q = 0; q < 4; ++q) val[q] = bb;
            for (int c = 0; c < 64; ++c) {
                float w = W_s2[c * 256 + col];
                #pragma unroll
                for (int q = 0; q < 4; ++q)
                    val[q] = fmaf(sB[glo + 2 * q][c], w, val[q]);
            }
            #pragma unroll
            for (int q = 0; q < 4; ++q) {
                int g = g0 + glo + 2 * q;
                T[g * 256 + col] = f2bf_rne(ssp(val[q]));
            }
        }
    }
}

// ---------------------------------------------------------------------------
// gather: j-split x4 for occupancy. 2048 blocks x 256 thr (8 blocks/CU).
// Block (rq, jq): 4 rows r0..r0+3, j in [jq*64, jq*64+64).
//   part[jq][r][d] = sum_{j in quarter} T[k(r,j)][d] * v1[b,j,d]
// h = t>>6 row (wave-uniform), p = t&63 owns dims 4p..4p+3.
// ---------------------------------------------------------------------------
__global__ __launch_bounds__(256) void gather_kernel(
    const float* __restrict__ dist, const float* __restrict__ v1,
    const uint16_t* __restrict__ T, float* __restrict__ part) {
    __shared__ uint32_t sk[4][64];
    const int t = threadIdx.x;
    const int rq = blockIdx.x >> 2;
    const int jq = blockIdx.x & 3;
    const int r0 = rq * 4;
    const int b = r0 >> 8;
    const int j0 = jq * 64;

    {   // one sk element per thread
        int row = t >> 6, j = t & 63;
        float d = dist[(r0 + row) * 256 + j0 + j];
        int k = (int)fmaf(d, 400.f, 0.5f);   // nearest grid point, step 0.0025
        k = min(k, 4095);
        sk[row][j] = (uint32_t)(k << 9);     // byte offset (512 B per table row)
    }
    __syncthreads();

    const int h = t >> 6;
    const int p = t & 63;
    float a0 = 0.f, a1 = 0.f, a2 = 0.f, a3 = 0.f;
    const char* Tp = (const char*)T + (p << 3);
    const float* vb = v1 + ((size_t)b << 16) + (size_t)j0 * 256 + (p << 2);

    #pragma unroll 4
    for (int jj = 0; jj < 64; jj += 4) {
        const uint4 kk = *(const uint4*)&sk[h][jj];
        const uint2 u0 = *(const uint2*)(Tp + kk.x);
        const uint2 u1 = *(const uint2*)(Tp + kk.y);
        const uint2 u2 = *(const uint2*)(Tp + kk.z);
        const uint2 u3 = *(const uint2*)(Tp + kk.w);
        const float4 w0 = *(const float4*)(vb + ((jj + 0) << 8));
        const float4 w1 = *(const float4*)(vb + ((jj + 1) << 8));
        const float4 w2 = *(const float4*)(vb + ((jj + 2) << 8));
        const float4 w3 = *(const float4*)(vb + ((jj + 3) << 8));
        a0 = fmaf(bf_lo(u0.x), w0.x, a0);
        a1 = fmaf(bf_hi(u0.x), w0.y, a1);
        a2 = fmaf(bf_lo(u0.y), w0.z, a2);
        a3 = fmaf(bf_hi(u0.y), w0.w, a3);
        a0 = fmaf(bf_lo(u1.x), w1.x, a0);
        a1 = fmaf(bf_hi(u1.x), w1.y, a1);
        a2 = fmaf(bf_lo(u1.y), w1.z, a2);
        a3 = fmaf(bf_hi(u1.y), w1.w, a3);
        a0 = fmaf(bf_lo(u2.x), w2.x, a0);
        a1 = fmaf(bf_hi(u2.x), w2.y, a1);
        a2 = fmaf(bf_lo(u2.y), w2.z, a2);
        a3 = fmaf(bf_hi(u2.y), w2.w, a3);
        a0 = fmaf(bf_lo(u3.x), w3.x, a0);
        a1 = fmaf(bf_hi(u3.x), w3.y, a1);
        a2 = fmaf(bf_lo(u3.y), w3.z, a2);
        a3 = fmaf(bf_hi(u3.y), w3.w, a3);
    }
    float* dst = part + (size_t)(jq * 2048 + r0 + h) * 256 + (p << 2);
    *(float4*)dst = make_float4(a0, a1, a2, a3);
}

// ---------------------------------------------------------------------------
// out: 512 blocks x 512 thr (8 waves, 2 blocks/CU -> 16 waves/CU).
// k-split halves (g = t>>8) with LDS reduce:
//   mid = (sum_q part[q]) * m ;  y = ssp(mid@W_a2 + b_a2)*m ; out = (y@W_a3+b_a3)*m
// ---------------------------------------------------------------------------
__global__ __launch_bounds__(512) void out_kernel(
    const float* __restrict__ part, const float* __restrict__ mask,
    const float* __restrict__ W_a2, const float* __restrict__ b_a2,
    const float* __restrict__ W_a3, const float* __restrict__ b_a3,
    float* __restrict__ out) {
    __shared__ float xs[4][256];
    __shared__ float red[4][256];
    const int t = threadIdx.x;
    const int r0 = blockIdx.x * 4;
    const int col = t & 255;
    const int g = t >> 8;            // k-half
    const int kbase = g * 128;
    const int c0 = blockIdx.x & 7;   // chunk rotation (8 chunks of 16 per half)

    #pragma unroll
    for (int rr2 = 0; rr2 < 2; ++rr2) {   // 2 rows per thread
        const int rr = g * 2 + rr2;
        const int r = r0 + rr;
        float s = part[(size_t)(0 * 2048 + r) * 256 + col]
                + part[(size_t)(1 * 2048 + r) * 256 + col]
                + part[(size_t)(2 * 2048 + r) * 256 + col]
                + part[(size_t)(3 * 2048 + r) * 256 + col];
        xs[rr][col] = s * mask[r];
    }
    __syncthreads();

    // ---------------- a2 (k-split) ----------------
    float acc[4] = {0.f, 0.f, 0.f, 0.f};
    {
        float w[16], wn[16];
        {
            const int kt = kbase + c0 * 16;
            #pragma unroll
            for (int q = 0; q < 16; ++q) w[q] = W_a2[(kt + q) * 256 + col];
        }
        for (int i = 0; i < 8; ++i) {
            const int kt = kbase + ((c0 + i) & 7) * 16;
            if (i < 7) {
                const int ktn = kbase + ((c0 + i + 1) & 7) * 16;
                #pragma unroll
                for (int q = 0; q < 16; ++q) wn[q] = W_a2[(ktn + q) * 256 + col];
            }
            #pragma unroll
            for (int q4 = 0; q4 < 4; ++q4) {
                const int k = kt + q4 * 4;
                const float w0 = w[q4 * 4 + 0], w1 = w[q4 * 4 + 1];
                const float w2 = w[q4 * 4 + 2], w3 = w[q4 * 4 + 3];
                #pragma unroll
                for (int rr = 0; rr < 4; ++rr) {
                    const float4 xv = *(const float4*)&xs[rr][k];
                    float a = acc[rr];
                    a = fmaf(xv.x, w0, a);
                    a = fmaf(xv.y, w1, a);
                    a = fmaf(xv.z, w2, a);
                    a = fmaf(xv.w, w3, a);
                    acc[rr] = a;
                }
            }
            if (i < 7) {
                #pragma unroll
                for (int q = 0; q < 16; ++q) w[q] = wn[q];
            }
        }
    }
    if (g == 1) {
        #pragma unroll
        for (int rr = 0; rr < 4; ++rr) red[rr][col] = acc[rr];
    }
    __syncthreads();
    if (g == 0) {
        const float b2 = b_a2[col];
        #pragma unroll
        for (int rr = 0; rr < 4; ++rr) {
            float a = acc[rr] + red[rr][col] + b2;
            xs[rr][col] = ssp(a) * mask[r0 + rr];
        }
    }
    __syncthreads();

    // ---------------- a3 (k-split) ----------------
    float acc3[4] = {0.f, 0.f, 0.f, 0.f};
    {
        float w[16], wn[16];
        {
            const int kt = kbase + c0 * 16;
            #pragma unroll
            for (int q = 0; q < 16; ++q) w[q] = W_a3[(kt + q) * 256 + col];
        }
        for (int i = 0; i < 8; ++i) {
            const int kt = kbase + ((c0 + i) & 7) * 16;
            if (i < 7) {
                const int ktn = kbase + ((c0 + i + 1) & 7) * 16;
                #pragma unroll
                for (int q = 0; q < 16; ++q) wn[q] = W_a3[(ktn + q) * 256 + col];
            }
            #pragma unroll
            for (int q4 = 0; q4 < 4; ++q4) {
                const int k = kt + q4 * 4;
                const float w0 = w[q4 * 4 + 0], w1 = w[q4 * 4 + 1];
                const float w2 = w[q4 * 4 + 2], w3 = w[q4 * 4 + 3];
                #pragma unroll
                for (int rr = 0; rr < 4; ++rr) {
                    const float4 xv = *(const float4*)&xs[rr][k];
                    float a = acc3[rr];
                    a = fmaf(xv.x, w0, a);
                    a = fmaf(xv.y, w1, a);
                    a = fmaf(xv.z, w2, a);
                    a = fmaf(xv.w, w3, a);
                    acc3[rr] = a;
                }
            }
            if (i < 7) {
                #pragma unroll
                for (int q = 0; q < 16; ++q) w[q] = wn[q];
            }
        }
    }
    if (g == 1) {
        #pragma unroll
        for (int rr = 0; rr < 4; ++rr) red[rr][col] = acc3[rr];
    }
    __syncthreads();
    if (g == 0) {
        const float b3 = b_a3[col];
        #pragma unroll
        for (int rr = 0; rr < 4; ++rr) {
            const int r = r0 + rr;
            out[r * 256 + col] = (acc3[rr] + red[rr][col] + b3) * mask[r];
        }
    }
}

// ---------------------------------------------------------------------------
extern "C" void kernel_launch(void* const* d_in, const int* in_sizes, int n_in,
                              void* d_out, int out_size, void* d_ws, size_t ws_size,
                              hipStream_t stream) {
    const float* v    = (const float*)d_in[0];
    const float* dist = (const float*)d_in[1];
    const float* mask = (const float*)d_in[2];
    const float* W_s1 = (const float*)d_in[3];
    const float* b_s1 = (const float*)d_in[4];
    const float* W_s2 = (const float*)d_in[5];
    const float* b_s2 = (const float*)d_in[6];
    const float* W_a1 = (const float*)d_in[7];
    const float* b_a1 = (const float*)d_in[8];
    const float* W_a2 = (const float*)d_in[9];
    const float* b_a2 = (const float*)d_in[10];
    const float* W_a3 = (const float*)d_in[11];
    const float* b_a3 = (const float*)d_in[12];
    float* out = (float*)d_out;

    char* ws = (char*)d_ws;
    float*    v1   = (float*)(ws);                   // 2 MB
    uint16_t* T    = (uint16_t*)(ws + (2u << 20));   // 2 MB bf16 [4096][256]
    float*    part = (float*)(ws + (4u << 20));      // 8 MB f32 [4][2048][256]

    prep_kernel<<<768, 512, 0, stream>>>(v, mask, W_a1, b_a1, W_s1, b_s1, W_s2, b_s2, v1, T);
    gather_kernel<<<2048, 256, 0, stream>>>(dist, v1, T, part);
    out_kernel<<<512, 512, 0, stream>>>(part, mask, W_a2, b_a2, W_a3, b_a3, out);
}